// Round 14
// baseline (456.883 us; speedup 1.0000x reference)
//
#include <hip/hip_runtime.h>
#include <stdint.h>

typedef _Float16 f16x8 __attribute__((ext_vector_type(8)));
typedef _Float16 f16x4 __attribute__((ext_vector_type(4)));
typedef _Float16 f16x2 __attribute__((ext_vector_type(2)));
typedef float fx4 __attribute__((ext_vector_type(4)));

static constexpr int S_LEN = 2048;
static constexpr int BATCH = 2;
static constexpr int TOKENS = BATCH * S_LEN;   // 4096
static constexpr int DIM = 2048;
static constexpr int NH = 16;
static constexpr int QR = 1536;
static constexpr int KVR = 512;
static constexpr int DN = 128;
static constexpr int DR = 64;
static constexpr int DV = 128;

// async global->LDS, 16B per lane; LDS dest = wave-uniform base, HW adds lane*16
__device__ __forceinline__ void async16(const _Float16* g, _Float16* lds_base_uniform) {
  __builtin_amdgcn_global_load_lds(
      (const __attribute__((address_space(1))) void*)g,
      (__attribute__((address_space(3))) void*)lds_base_uniform, 16, 0, 0);
}

// raw barrier WITHOUT the implicit vmcnt(0) drain of __syncthreads
__device__ __forceinline__ void bar() {
  asm volatile("" ::: "memory");
  __builtin_amdgcn_s_barrier();
  asm volatile("" ::: "memory");
}
#define VMWAIT(n) asm volatile("s_waitcnt vmcnt(" #n ")" ::: "memory")

// sin/cos via v_sin/v_cos (input = revolutions), manual range reduction
__device__ __forceinline__ void sincos_rev(float ang, float* sn, float* cs) {
  float rev = ang * 0.15915494309189535f;
  rev -= floorf(rev);
  *sn = __builtin_amdgcn_sinf(rev);   // sin(2*pi*rev)
  *cs = __builtin_amdgcn_cosf(rev);
}

// ------- fused f32 -> f16 conversion (+ norm fold; seg with src=null zeroes)
struct CvtSegs {
  const float* src[9];
  _Float16* dst[9];
  const float* nw[9];   // per-column weight to fold (or nullptr)
  int nmod[9];          // column count (multiple of 4)
  int n4[9];
  int cum[10];
};
__global__ __launch_bounds__(256) void cvt_all(CvtSegs s) {
  const int b = blockIdx.x;
  int seg = 0;
#pragma unroll
  for (int k = 0; k < 8; ++k) seg += (b >= s.cum[seg + 1]) ? 1 : 0;
  const int i = (b - s.cum[seg]) * 256 + threadIdx.x;
  if (i >= s.n4[seg]) return;
  if (!s.src[seg]) {                    // zero-fill segment (sums buffers)
    f16x4 z;
    z[0] = (_Float16)0.f; z[1] = (_Float16)0.f;
    z[2] = (_Float16)0.f; z[3] = (_Float16)0.f;
    *(f16x4*)(s.dst[seg] + (size_t)i * 4) = z;
    return;
  }
  fx4 v = *(const fx4*)(s.src[seg] + (size_t)i * 4);
  if (s.nw[seg]) {
    const int c0 = (int)(((size_t)i * 4) % (size_t)s.nmod[seg]);
    fx4 wv = *(const fx4*)(s.nw[seg] + c0);
    v[0] *= wv[0]; v[1] *= wv[1]; v[2] *= wv[2]; v[3] *= wv[3];
  }
  f16x4 o;
  o[0] = (_Float16)v[0]; o[1] = (_Float16)v[1];
  o[2] = (_Float16)v[2]; o[3] = (_Float16)v[3];
  *(f16x4*)(s.dst[seg] + (size_t)i * 4) = o;
}

// ---------------- 128x128 NT GEMM: down-projection (R11-verified) ----------
__global__ __launch_bounds__(256) void gemm_down(const _Float16* __restrict__ A,
                                                 const _Float16* __restrict__ W,
                                                 _Float16* __restrict__ qc,
                                                 _Float16* __restrict__ kvc,
                                                 _Float16* __restrict__ kr,
                                                 float* __restrict__ sums_q,
                                                 float* __restrict__ sums_kv) {
  __shared__ __attribute__((aligned(16))) _Float16 As[3][128 * 32];
  __shared__ __attribute__((aligned(16))) _Float16 Ws[3][128 * 32];
  const int tid = threadIdx.x;
  const int lane = tid & 63;
  const int wave = tid >> 6;
  const int wr = (wave >> 1) * 64;
  const int wc = (wave & 1) * 64;
  const int m16 = lane & 15;
  const int quad = lane >> 4;
  const int swz = (m16 >> 1) & 3;
  const int m0 = blockIdx.y * 128;
  const int n0 = blockIdx.x * 128;
  const int K = DIM;

  auto stage = [&](int buf, int k0) {
#pragma unroll
    for (int p = 0; p < 2; ++p) {
      const int cb = p * 256 + wave * 64;
      const int ch = cb + lane;
      const int r = ch >> 2;
      const int c8 = ((ch & 3) ^ ((r >> 1) & 3)) * 8;
      async16(A + (size_t)(m0 + r) * K + k0 + c8, &As[buf][cb * 8]);
      async16(W + (size_t)(n0 + r) * K + k0 + c8, &Ws[buf][cb * 8]);
    }
  };

  const fx4 fz = {0.f, 0.f, 0.f, 0.f};
  fx4 acc[4][4];
#pragma unroll
  for (int i = 0; i < 4; ++i)
#pragma unroll
    for (int j = 0; j < 4; ++j) acc[i][j] = fz;

  const int nkt = K >> 5;
  stage(0, 0);
  stage(1, 32);
  int cur = 0;
  for (int kt = 0; kt < nkt; ++kt) {
    if (kt + 1 < nkt) { VMWAIT(4); } else { VMWAIT(0); }
    bar();
    if (kt + 2 < nkt) {
      int b2 = cur + 2; if (b2 >= 3) b2 -= 3;
      stage(b2, (kt + 2) * 32);
    }
    const _Float16* as = As[cur];
    const _Float16* ws = Ws[cur];
    f16x8 af[4], wf[4];
#pragma unroll
    for (int i = 0; i < 4; ++i)
      af[i] = *(const f16x8*)(&as[((wr + i * 16 + m16) * 4 + (quad ^ swz)) * 8]);
#pragma unroll
    for (int j = 0; j < 4; ++j)
      wf[j] = *(const f16x8*)(&ws[((wc + j * 16 + m16) * 4 + (quad ^ swz)) * 8]);
#pragma unroll
    for (int i = 0; i < 4; ++i)
#pragma unroll
      for (int j = 0; j < 4; ++j)
        acc[i][j] = __builtin_amdgcn_mfma_f32_16x16x32_f16(af[i], wf[j], acc[i][j], 0, 0, 0);
    if (++cur == 3) cur = 0;
  }

#pragma unroll
  for (int j = 0; j < 4; ++j) {
    const int col = n0 + wc + j * 16 + m16;
    if (col < 2048) {
#pragma unroll
      for (int i = 0; i < 4; ++i)
#pragma unroll
        for (int r = 0; r < 4; ++r) {
          const size_t row = (size_t)(m0 + wr + i * 16 + quad * 4 + r);
          const _Float16 v = (_Float16)acc[i][j][r];
          if (col < 1536) qc[row * 1536 + col] = v;
          else            kvc[row * 512 + col - 1536] = v;
        }
    } else if (col < 2112) {
      const int d = col - 2048;
      const int pidx = d >> 1;
      const bool odd = (d & 1);
      const float fr = exp2f(-(float)pidx * 0.4152410118609203f);
#pragma unroll
      for (int i = 0; i < 4; ++i)
#pragma unroll
        for (int r = 0; r < 4; ++r) {
          const size_t row = (size_t)(m0 + wr + i * 16 + quad * 4 + r);
          const int spos = (int)(row & (S_LEN - 1));
          float sn, cs;
          sincos_rev((float)spos * fr, &sn, &cs);
          const float own = acc[i][j][r];
          const float oth = __shfl_xor(own, 1);
          const float res = odd ? (oth * sn + own * cs) : (own * cs - oth * sn);
          kr[row * 64 + d] = (_Float16)res;
        }
    }
  }

  if (n0 < 2048) {
    float* sums = (n0 < 1536) ? sums_q : sums_kv;
#pragma unroll
    for (int i = 0; i < 4; ++i)
#pragma unroll
      for (int r = 0; r < 4; ++r) {
        float p = 0.f;
#pragma unroll
        for (int j = 0; j < 4; ++j) p += acc[i][j][r] * acc[i][j][r];
        p += __shfl_xor(p, 1);
        p += __shfl_xor(p, 2);
        p += __shfl_xor(p, 4);
        p += __shfl_xor(p, 8);
        if (m16 == 0)
          atomicAdd(&sums[m0 + wr + i * 16 + quad * 4 + r], p);
      }
  }
}

// ---------------- 256x256 8-wave 4-phase GEMM: up-projections --------------
__global__ __launch_bounds__(512, 2) void gemm256_up(
    const _Float16* __restrict__ qc, const _Float16* __restrict__ wqu,
    const _Float16* __restrict__ kvc, const _Float16* __restrict__ wkvu,
    const float* __restrict__ sums_q, const float* __restrict__ sums_kv,
    _Float16* __restrict__ qnope, _Float16* __restrict__ qpe,
    _Float16* __restrict__ knope, _Float16* __restrict__ vT) {
  __shared__ __attribute__((aligned(16))) _Float16 As[2][256 * 64];  // 64 KB
  __shared__ __attribute__((aligned(16))) _Float16 Ws[2][256 * 64];  // 64 KB

  const int tid = threadIdx.x;
  const int lane = tid & 63;
  const int wave = tid >> 6;           // 0..7
  const int wrow = wave >> 2;          // 0..1
  const int wcol = wave & 3;           // 0..3
  const int m16 = lane & 15;
  const int quad = lane >> 4;
  const int m0 = blockIdx.y * 256;

  const bool isq = ((int)blockIdx.x < 12);
  const int n0 = (isq ? blockIdx.x : blockIdx.x - 12) * 256;
  const _Float16* A = isq ? qc : kvc;
  const _Float16* W = isq ? wqu : wkvu;
  const int K = isq ? QR : KVR;

  auto stageHalf = [&](int buf, int k0, int tensor, int h) {
#pragma unroll
    for (int k = 0; k < 2; ++k) {
      const int cb = (wave * 2 + k) * 64;      // chunk base in half (0..1023)
      const int ch = cb + lane;
      const int r = ch >> 3;                   // local row 0..127
      const int gc = (ch & 7) ^ (r & 7);       // pre-swizzled source chunk
      const int grow = h * 128 + r;
      if (tensor == 0)
        async16(A + (size_t)(m0 + grow) * K + k0 + gc * 8,
                &As[buf][(h * 1024 + cb) * 8]);
      else
        async16(W + (size_t)(n0 + grow) * K + k0 + gc * 8,
                &Ws[buf][(h * 1024 + cb) * 8]);
    }
  };

  const fx4 fz = {0.f, 0.f, 0.f, 0.f};
  fx4 acc[8][4];
#pragma unroll
  for (int i = 0; i < 8; ++i)
#pragma unroll
    for (int j = 0; j < 4; ++j) acc[i][j] = fz;

  f16x8 af[4][2], wf0[2][2], wf1[2][2];

  auto rdA = [&](const _Float16* as, int mh) {
#pragma unroll
    for (int mg = 0; mg < 4; ++mg)
#pragma unroll
      for (int ks = 0; ks < 2; ++ks) {
        const int row = mh * 128 + mg * 32 + wrow * 16 + m16;
        af[mg][ks] = *(const f16x8*)(&as[(row * 8 + ((ks * 4 + quad) ^ (m16 & 7))) * 8]);
      }
  };
  auto rdB = [&](const _Float16* ws, int nh, f16x8 wf[2][2]) {
#pragma unroll
    for (int ng = 0; ng < 2; ++ng)
#pragma unroll
      for (int ks = 0; ks < 2; ++ks) {
        const int row = nh * 128 + ng * 64 + wcol * 16 + m16;
        wf[ng][ks] = *(const f16x8*)(&ws[(row * 8 + ((ks * 4 + quad) ^ (m16 & 7))) * 8]);
      }
  };
  auto quadMFMA = [&](int mh, int nh, f16x8 wf[2][2]) {
    __builtin_amdgcn_s_setprio(1);
#pragma unroll
    for (int ks = 0; ks < 2; ++ks)
#pragma unroll
      for (int mg = 0; mg < 4; ++mg)
#pragma unroll
        for (int ng = 0; ng < 2; ++ng)
          acc[mh * 4 + mg][nh * 2 + ng] = __builtin_amdgcn_mfma_f32_16x16x32_f16(
              af[mg][ks], wf[ng][ks], acc[mh * 4 + mg][nh * 2 + ng], 0, 0, 0);
    __builtin_amdgcn_s_setprio(0);
  };

  const int nkt = K >> 6;
  stageHalf(0, 0, 0, 0);
  stageHalf(0, 0, 1, 0);
  stageHalf(0, 0, 1, 1);
  stageHalf(0, 0, 0, 1);

  for (int t = 0; t < nkt; ++t) {
    const int cur = t & 1;
    const int nb = cur ^ 1;
    const int k0n = (t + 1) * 64;
    const bool more = (t + 1 < nkt);
    const _Float16* as = As[cur];
    const _Float16* ws = Ws[cur];

    VMWAIT(4);
    bar();
    rdA(as, 0);
    rdB(ws, 0, wf0);
    if (more) stageHalf(nb, k0n, 0, 0);      // Ah0(t+1)
    quadMFMA(0, 0, wf0);

    if (more) { VMWAIT(4); } else { VMWAIT(2); }
    bar();
    rdB(ws, 1, wf1);
    if (more) stageHalf(nb, k0n, 1, 0);      // Bh0(t+1)
    quadMFMA(0, 1, wf1);

    if (more) { VMWAIT(4); } else { VMWAIT(0); }
    bar();
    rdA(as, 1);
    if (more) stageHalf(nb, k0n, 1, 1);      // Bh1(t+1)
    quadMFMA(1, 1, wf1);

    bar();
    if (more) stageHalf(nb, k0n, 0, 1);      // Ah1(t+1)
    quadMFMA(1, 0, wf0);
  }

  const float* rs = isq ? sums_q : sums_kv;
  const float invNC = isq ? (1.0f / (float)QR) : (1.0f / (float)KVR);
  float rsq[8][4];
#pragma unroll
  for (int mg = 0; mg < 8; ++mg)
#pragma unroll
    for (int r = 0; r < 4; ++r)
      rsq[mg][r] = rsqrtf(rs[m0 + mg * 32 + wrow * 16 + quad * 4 + r] * invNC + 1e-6f);

#pragma unroll
  for (int ng = 0; ng < 4; ++ng) {
    const int col = n0 + ng * 64 + wcol * 16 + m16;
    if (isq) {
#pragma unroll
      for (int mg = 0; mg < 8; ++mg)
#pragma unroll
        for (int r = 0; r < 4; ++r) {
          const size_t row = (size_t)(m0 + mg * 32 + wrow * 16 + quad * 4 + r);
          const _Float16 v = (_Float16)(acc[mg][ng][r] * rsq[mg][r]);
          if (col < 2048) qnope[row * 2048 + col] = v;
          else qpe[row * 1024 + col - 2048] = v;
        }
    } else {
      const int head = col >> 8;
      const int sub = col & 255;
      if (sub < 128) {
#pragma unroll
        for (int mg = 0; mg < 8; ++mg)
#pragma unroll
          for (int r = 0; r < 4; ++r) {
            const size_t row = (size_t)(m0 + mg * 32 + wrow * 16 + quad * 4 + r);
            knope[row * 2048 + head * 128 + sub] =
                (_Float16)(acc[mg][ng][r] * rsq[mg][r]);
          }
      } else {
        const int dv = sub - 128;
#pragma unroll
        for (int mg = 0; mg < 8; ++mg) {
          f16x4 v;
#pragma unroll
          for (int r = 0; r < 4; ++r) v[r] = (_Float16)(acc[mg][ng][r] * rsq[mg][r]);
          *(f16x4*)(&vT[(size_t)(head * 128 + dv) * TOKENS + m0 +
                        mg * 32 + wrow * 16 + quad * 4]) = v;
        }
      }
    }
  }
}

// ---------------- 128x256 8-wave 2-phase GEMM (out-proj, verified R11) -----
__global__ __launch_bounds__(512, 1) void gemm_out(
    const _Float16* __restrict__ A,    // attn [4096, 2048]
    const _Float16* __restrict__ W,    // wo   [2048, 2048]
    float* __restrict__ C) {           // out  [4096, 2048] f32
  __shared__ __attribute__((aligned(16))) _Float16 As[2][128 * 64];  // 32 KB
  __shared__ __attribute__((aligned(16))) _Float16 Ws[2][256 * 64];  // 64 KB

  const int tid = threadIdx.x;
  const int lane = tid & 63;
  const int wave = tid >> 6;           // 0..7
  const int wrow = wave >> 2;          // 0..1
  const int wcol = wave & 3;           // 0..3
  const int m16 = lane & 15;
  const int quad = lane >> 4;
  const int m0 = blockIdx.y * 128;
  const int n0 = blockIdx.x * 256;
  const int K = NH * DV;               // 2048

  auto stageA = [&](int buf, int k0) {
#pragma unroll
    for (int k = 0; k < 2; ++k) {
      const int cb = (wave * 2 + k) * 64;
      const int ch = cb + lane;
      const int r = ch >> 3;
      const int gc = (ch & 7) ^ (r & 7);
      async16(A + (size_t)(m0 + r) * K + k0 + gc * 8, &As[buf][cb * 8]);
    }
  };
  auto stageW = [&](int buf, int k0, int h) {
#pragma unroll
    for (int k = 0; k < 2; ++k) {
      const int cb = (wave * 2 + k) * 64;
      const int ch = cb + lane;
      const int r = ch >> 3;
      const int gc = (ch & 7) ^ (r & 7);
      async16(W + (size_t)(n0 + h * 128 + r) * K + k0 + gc * 8,
              &Ws[buf][(h * 1024 + cb) * 8]);
    }
  };

  const fx4 fz = {0.f, 0.f, 0.f, 0.f};
  fx4 acc[4][4];
#pragma unroll
  for (int i = 0; i < 4; ++i)
#pragma unroll
    for (int j = 0; j < 4; ++j) acc[i][j] = fz;

  f16x8 af[4][2], wf0[2][2], wf1[2][2];

  auto rdA = [&](const _Float16* as) {
#pragma unroll
    for (int mg = 0; mg < 4; ++mg)
#pragma unroll
      for (int ks = 0; ks < 2; ++ks) {
        const int row = mg * 32 + wrow * 16 + m16;
        af[mg][ks] = *(const f16x8*)(&as[(row * 8 + ((ks * 4 + quad) ^ (m16 & 7))) * 8]);
      }
  };
  auto rdB = [&](const _Float16* ws, int nh, f16x8 wf[2][2]) {
#pragma unroll
    for (int ng = 0; ng < 2; ++ng)
#pragma unroll
      for (int ks = 0; ks < 2; ++ks) {
        const int row = nh * 128 + ng * 64 + wcol * 16 + m16;
        wf[ng][ks] = *(const f16x8*)(&ws[(row * 8 + ((ks * 4 + quad) ^ (m16 & 7))) * 8]);
      }
  };
  auto halfMFMA = [&](int nh, f16x8 wf[2][2]) {
    __builtin_amdgcn_s_setprio(1);
#pragma unroll
    for (int ks = 0; ks < 2; ++ks)
#pragma unroll
      for (int mg = 0; mg < 4; ++mg)
#pragma unroll
        for (int ng = 0; ng < 2; ++ng)
          acc[mg][nh * 2 + ng] = __builtin_amdgcn_mfma_f32_16x16x32_f16(
              af[mg][ks], wf[ng][ks], acc[mg][nh * 2 + ng], 0, 0, 0);
    __builtin_amdgcn_s_setprio(0);
  };

  const int nkt = K >> 6;              // 32
  stageA(0, 0);
  stageW(0, 0, 0);
  stageW(0, 0, 1);

  for (int t = 0; t < nkt; ++t) {
    const int cur = t & 1;
    const int nb = cur ^ 1;
    const int k0n = (t + 1) * 64;
    const bool more = (t + 1 < nkt);
    const _Float16* as = As[cur];
    const _Float16* ws = Ws[cur];

    VMWAIT(2);
    bar();
    rdA(as);
    rdB(ws, 0, wf0);
    if (more) stageA(nb, k0n);
    halfMFMA(0, wf0);

    if (more) { VMWAIT(2); } else { VMWAIT(0); }
    bar();
    rdB(ws, 1, wf1);
    if (more) { stageW(nb, k0n, 0); stageW(nb, k0n, 1); }
    halfMFMA(1, wf1);
  }

#pragma unroll
  for (int ng = 0; ng < 4; ++ng) {
    const int col = n0 + ng * 64 + wcol * 16 + m16;
#pragma unroll
    for (int mg = 0; mg < 4; ++mg)
#pragma unroll
      for (int r = 0; r < 4; ++r) {
        const size_t row = (size_t)(m0 + mg * 32 + wrow * 16 + quad * 4 + r);
        C[row * 2048 + col] = acc[mg][ng][r];
      }
  }
}

// ---------------- causal flash attention v10: swapped QK^T -----------------
// mfma(K, Q) instead of mfma(Q, K): output lane.m16 = q-row, quad*4+r = key.
// Softmax is LANE-LOCAL (one q-row per lane, scalar m): 7 fmax + 2 shfl_xor
// replaces the per-row DPP chains; P redistributes to the PV A-layout via
// in-register shfl (dest quad d takes keys 8d..8d+7 = src quads (2d)&3,
// (2d+1)&3 of group d>>1) — the Ps LDS roundtrip is DELETED (LDS 51->41KB).
// l-sum via ones-column MFMA and oacc/epilogue layout unchanged.
__global__ __launch_bounds__(512, 2) void mla_attn(
    const _Float16* __restrict__ qn,   // [T, NH*128]
    const _Float16* __restrict__ qp,   // [T, NH*64]  RAW (rope applied here)
    const _Float16* __restrict__ kn,   // [T, NH*128]
    const _Float16* __restrict__ kr,   // [T, 64]     roped
    const _Float16* __restrict__ vT,   // [NH*128, T]
    _Float16* __restrict__ out)        // [T, NH*128]
{
  __shared__ __attribute__((aligned(16))) _Float16 Ks[2][768 * 8];  // 24 KB
  __shared__ __attribute__((aligned(16))) _Float16 Vs[2][512 * 8];  // 16 KB

  const int bid = blockIdx.x;          // 512 = 16 q-tiles (longest first) x 32 (b,h)
  const int j = bid >> 5;
  const int bh = bid & 31;
  const int b = bh >> 4;
  const int h = bh & 15;
  const int q16 = 15 - j;              // longest-first
  const int qb = q16 * 128;
  const int tok0 = b * S_LEN;

  const int tid = threadIdx.x;
  const int lane = tid & 63;
  const int wave = tid >> 6;           // 0..7
  const int m16 = lane & 15;
  const int quad = lane >> 4;
  const int R0 = qb + wave * 16;

  auto stageKV = [&](int buf, int kbase) {
#pragma unroll
    for (int jj = 0; jj < 3; ++jj) {
      const int idx = wave * 3 + jj;          // 0..23; 20 used
      if (idx < 12) {
        const int ch = idx * 2 + (lane >> 5);
        const int key = lane & 31;
        const _Float16* g = (ch < 16)
            ? kn + (size_t)(tok0 + kbase + key) * 2048 + h * 128 + ch * 8
            : kr + (size_t)(tok0 + kbase + key) * 64 + (ch - 16) * 8;
        async16(g, &Ks[buf][idx * 512]);
      } else if (idx < 20) {
        const int iv = idx - 12;              // 0..7
        const int p = iv * 64 + lane;
        const int L = p ^ ((p >> 3) & 3);     // involutive source pre-swizzle
        const int dv = L >> 2;
        const int qcc = L & 3;
        async16(vT + (size_t)(h * 128 + dv) * TOKENS + tok0 + kbase + qcc * 8,
                &Vs[buf][iv * 512]);
      }
    }
  };

  const float scale2 = 0.07216878364870323f * 1.4426950408889634f;  // /sqrt(192), log2 dom
  const fx4 fz = {0.f, 0.f, 0.f, 0.f};

  // ---- Q fragments (row = m16; serves as the B operand after the swap) ----
  f16x8 qf[6];
  {
    const int srow = qb + wave * 16 + m16;     // seq position (0..2047)
    const size_t t = (size_t)(tok0 + srow);
#pragma unroll
    for (int kk = 0; kk < 4; ++kk)
      qf[kk] = *(const f16x8*)(qn + t * 2048 + h * 128 + kk * 32 + quad * 8);
#pragma unroll
    for (int kk = 0; kk < 2; ++kk) {
      f16x8 v = *(const f16x8*)(qp + t * 1024 + h * 64 + kk * 32 + quad * 8);
      f16x8 o;
      const int i0 = kk * 16 + quad * 4;       // rope pair index base
#pragma unroll
      for (int jj = 0; jj < 4; ++jj) {
        const float ang = (float)srow * exp2f(-(float)(i0 + jj) * 0.4152410118609203f);
        float sn, cs;
        sincos_rev(ang, &sn, &cs);
        const float x1 = (float)v[2 * jj], x2 = (float)v[2 * jj + 1];
        o[2 * jj]     = (_Float16)(x1 * cs - x2 * sn);
        o[2 * jj + 1] = (_Float16)(x1 * sn + x2 * cs);
      }
      qf[4 + kk] = o;
    }
  }

  fx4 oacc[9];                         // [8] accumulates row-sums (P x ones)
#pragma unroll
  for (int n = 0; n < 9; ++n) oacc[n] = fz;
  float mst = -3.0e38f;                // scalar: this lane's q-row (m16) max
  f16x8 vones;
#pragma unroll
  for (int e = 0; e < 8; ++e) vones[e] = (_Float16)1.0f;

  const int nkt = (qb >> 5) + 4;       // key tiles: 0 .. qb+127 (4..64)

  stageKV(0, 0);
  for (int kt = 0; kt < nkt; ++kt) {
    const int kbase = kt * 32;
    __syncthreads();
    if (kt + 1 < nkt) stageKV((kt + 1) & 1, kbase + 32);

    const bool live = (kbase <= R0 + 15);
    if (!live) continue;
    const _Float16* ks = Ks[kt & 1];
    const _Float16* vs = Vs[kt & 1];

    // ---- S = K Q^T (swapped): lane m16 = q-row, quad*4+r = key ----
    fx4 sc[2];
    sc[0] = fz; sc[1] = fz;
    __builtin_amdgcn_s_setprio(1);
#pragma unroll
    for (int kk = 0; kk < 6; ++kk) {
#pragma unroll
      for (int n = 0; n < 2; ++n) {
        f16x8 kf = *(const f16x8*)(&ks[(kk * 128 + quad * 32 + n * 16 + m16) * 8]);
        sc[n] = __builtin_amdgcn_mfma_f32_16x16x32_f16(kf, qf[kk], sc[n], 0, 0, 0);
      }
    }
    __builtin_amdgcn_s_setprio(0);

    // V fragments from LDS (swizzled read)
    f16x8 vf[8];
#pragma unroll
    for (int n8 = 0; n8 < 8; ++n8) {
      const int c0 = (n8 * 16 + m16) * 4 + quad;
      vf[n8] = *(const f16x8*)(&vs[(c0 ^ ((c0 >> 3) & 3)) * 8]);
    }

    // ---- lane-local softmax (one q-row per lane) ----
    const bool needmask = (kbase + 31 > R0);
    const int qrow = R0 + m16;
    float v[8];
#pragma unroll
    for (int n = 0; n < 2; ++n)
#pragma unroll
      for (int r = 0; r < 4; ++r) {
        float s = sc[n][r] * scale2;
        if (needmask && (kbase + n * 16 + quad * 4 + r > qrow)) s = -3.0e38f;
        v[n * 4 + r] = s;
      }
    float mx = v[0];
#pragma unroll
    for (int e = 1; e < 8; ++e) mx = fmaxf(mx, v[e]);
    mx = fmaxf(mx, __shfl_xor(mx, 16));
    mx = fmaxf(mx, __shfl_xor(mx, 32));     // all quads of this m16 now agree
    float al = 1.0f;
    const bool upd = __any(mx > mst + 10.0f);  // defer-max
    if (upd) {
      const float mn = fmaxf(mst, mx);
      al = exp2f(mst - mn);                 // rows that didn't grow: al = 1
      mst = mn;
    }
    float p[8];
#pragma unroll
    for (int e = 0; e < 8; ++e) p[e] = exp2f(v[e] - mst);

    // pack to f16 pairs: pa = keys {quad*4+0..3}, pb = keys {16+quad*4+0..3}
    union { f16x2 h; uint32_t u; } cv;
    uint32_t pa0, pa1, pb0, pb1;
    cv.h[0] = (_Float16)p[0]; cv.h[1] = (_Float16)p[1]; pa0 = cv.u;
    cv.h[0] = (_Float16)p[2]; cv.h[1] = (_Float16)p[3]; pa1 = cv.u;
    cv.h[0] = (_Float16)p[4]; cv.h[1] = (_Float16)p[5]; pb0 = cv.u;
    cv.h[0] = (_Float16)p[6]; cv.h[1] = (_Float16)p[7]; pb1 = cv.u;

    // redistribute to PV A-layout: dest quad d wants keys 8d..8d+7
    const int srcA = m16 + 16 * ((2 * quad) & 3);
    const int srcB = m16 + 16 * ((2 * quad + 1) & 3);
    const uint32_t xa0 = (uint32_t)__shfl((int)pa0, srcA);
    const uint32_t xa1 = (uint32_t)__shfl((int)pa1, srcA);
    const uint32_t xa2 = (uint32_t)__shfl((int)pa0, srcB);
    const uint32_t xa3 = (uint32_t)__shfl((int)pa1, srcB);
    const uint32_t xb0 = (uint32_t)__shfl((int)pb0, srcA);
    const uint32_t xb1 = (uint32_t)__shfl((int)pb1, srcA);
    const uint32_t xb2 = (uint32_t)__shfl((int)pb0, srcB);
    const uint32_t xb3 = (uint32_t)__shfl((int)pb1, srcB);
    const bool g = (quad >> 1);             // quads 0,1 -> sc0 keys; 2,3 -> sc1
    union { uint32_t u[4]; f16x8 v; } pu;
    pu.u[0] = g ? xb0 : xa0;
    pu.u[1] = g ? xb1 : xa1;
    pu.u[2] = g ? xb2 : xa2;
    pu.u[3] = g ? xb3 : xa3;
    const f16x8 pf = pu.v;

    // alpha rescale (wave-uniform trigger; per-row alpha via shfl)
    if (upd) {
      float alr[4];
#pragma unroll
      for (int r = 0; r < 4; ++r) alr[r] = __shfl(al, quad * 4 + r);
#pragma unroll
      for (int n8 = 0; n8 < 9; ++n8)
#pragma unroll
        for (int r = 0; r < 4; ++r) oacc[n8][r] *= alr[r];
    }

    // ---- O += P V ; row-sums accumulate via ones-column MFMA ----
    __builtin_amdgcn_s_setprio(1);
#pragma unroll
    for (int n8 = 0; n8 < 8; ++n8)
      oacc[n8] = __builtin_amdgcn_mfma_f32_16x16x32_f16(pf, vf[n8], oacc[n8], 0, 0, 0);
    oacc[8] = __builtin_amdgcn_mfma_f32_16x16x32_f16(pf, vones, oacc[8], 0, 0, 0);
    __builtin_amdgcn_s_setprio(0);
  }

  // ---- epilogue: normalize by oacc[8] (row sums; all cols equal) ----
  float inv[4];
#pragma unroll
  for (int r = 0; r < 4; ++r) inv[r] = 1.0f / oacc[8][r];
#pragma unroll
  for (int n8 = 0; n8 < 8; ++n8) {
#pragma unroll
    for (int r = 0; r < 4; ++r) {
      const size_t t = (size_t)(tok0 + qb + wave * 16 + quad * 4 + r);
      out[t * 2048 + h * 128 + n8 * 16 + m16] = (_Float16)(oacc[n8][r] * inv[r]);
    }
  }
}

// ---------------- launch ----------------------------------------------------
extern "C" void kernel_launch(void* const* d_in, const int* in_sizes, int n_in,
                              void* d_out, int out_size, void* d_ws, size_t ws_size,
                              hipStream_t stream) {
  const float* x         = (const float*)d_in[0];
  const float* wq_down   = (const float*)d_in[1];
  const float* q_norm_w  = (const float*)d_in[2];
  const float* wq_up     = (const float*)d_in[3];
  const float* wq_rope   = (const float*)d_in[4];
  const float* wkv_down  = (const float*)d_in[5];
  const float* kv_norm_w = (const float*)d_in[6];
  const float* wkv_up    = (const float*)d_in[7];
  const float* wk_rope   = (const float*)d_in[8];
  const float* wo        = (const float*)d_in[9];
  float* out = (float*)d_out;

  char* ws = (char*)d_ws;
  size_t off = 0;
  auto alloc = [&](size_t bytes) {
    char* p = ws + off;
    off += (bytes + 255) & ~(size_t)255;
    return p;
  };
  _Float16* x_h     = (_Float16*)alloc((size_t)TOKENS * DIM * 2);
  _Float16* wA_h    = (_Float16*)alloc((size_t)2176 * DIM * 2);      // wq_down|wkv_down|wk_rope (+pad)
  _Float16* wquqr_h = (_Float16*)alloc((size_t)3072 * QR * 2);       // (wq_up|wq_rope) . q_norm
  _Float16* wkvu_h  = (_Float16*)alloc((size_t)NH * 256 * KVR * 2);  // wkv_up . kv_norm
  _Float16* wo_h    = (_Float16*)alloc((size_t)DIM * NH * DV * 2);
  _Float16* qc_h    = (_Float16*)alloc((size_t)TOKENS * QR * 2);     // RAW (un-normalized)
  _Float16* kvc_h   = (_Float16*)alloc((size_t)TOKENS * KVR * 2);    // RAW
  _Float16* qnope_h = (_Float16*)alloc((size_t)TOKENS * 2048 * 2);
  _Float16* qpe_h   = (_Float16*)alloc((size_t)TOKENS * 1024 * 2);
  _Float16* knope_h = (_Float16*)alloc((size_t)TOKENS * 2048 * 2);
  _Float16* vT_h    = (_Float16*)alloc((size_t)2048 * TOKENS * 2);
  _Float16* krope_h = (_Float16*)alloc((size_t)TOKENS * DR * 2);     // roped in down-proj
  _Float16* attn_h  = (_Float16*)alloc((size_t)TOKENS * 2048 * 2);
  float* sq_h       = (float*)alloc((size_t)TOKENS * 4);             // row sum(x^2) qc
  float* skv_h      = (float*)alloc((size_t)TOKENS * 4);             // row sum(x^2) kvc

  // ---- one fused conversion dispatch (also zeroes the sums buffers) -------
  CvtSegs cs;
  const float* srcs[9] = {x, wq_down, wq_up, wq_rope, wkv_down, wk_rope, wkv_up, wo,
                          nullptr};
  _Float16* dsts[9] = {x_h, wA_h, wquqr_h, wquqr_h + (size_t)2048 * QR,
                       wA_h + (size_t)1536 * DIM, wA_h + (size_t)2048 * DIM,
                       wkvu_h, wo_h, (_Float16*)sq_h};
  const float* nws[9] = {nullptr, nullptr, q_norm_w, q_norm_w, nullptr, nullptr,
                         kv_norm_w, nullptr, nullptr};
  const int nmods[9] = {4, 4, QR, QR, 4, 4, KVR, 4, 4};
  const size_t ns[9] = {(size_t)TOKENS * DIM, (size_t)QR * DIM, (size_t)2048 * QR,
                        (size_t)1024 * QR, (size_t)KVR * DIM, (size_t)DR * DIM,
                        (size_t)NH * 256 * KVR, (size_t)DIM * NH * DV,
                        (size_t)2 * TOKENS * 2};  // sq+skv contiguous (f16 units)
  int cum = 0;
  for (int i = 0; i < 9; ++i) {
    cs.src[i] = srcs[i];
    cs.dst[i] = dsts[i];
    cs.nw[i] = nws[i];
    cs.nmod[i] = nmods[i];
    cs.n4[i] = (int)(ns[i] / 4);
    cs.cum[i] = cum;
    cum += (cs.n4[i] + 255) / 256;
  }
  cs.cum[9] = cum;
  cvt_all<<<dim3(cum), 256, 0, stream>>>(cs);

  const unsigned gm = TOKENS / 128;

  // down-projection (128^2, 544 blocks, R11-verified): x -> qc|kvc|krope(+RoPE)
  // + fused row sum(x^2) atomics (replaces rownorm dispatch)
  gemm_down<<<dim3(17, gm), 256, 0, stream>>>(x_h, wA_h, qc_h, kvc_h, krope_h,
                                              sq_h, skv_h);
  // fused up-projections (256^2 4-phase): qc -> qnope|qpe ; kvc -> knope+vT
  gemm256_up<<<dim3(12 + 16, TOKENS / 256), 512, 0, stream>>>(
      qc_h, wquqr_h, kvc_h, wkvu_h, sq_h, skv_h,
      qnope_h, qpe_h, knope_h, vT_h);
  // attention: 512 blocks x 8 waves (128 q-rows each), longest-first
  mla_attn<<<dim3(512), 512, 0, stream>>>(qnope_h, qpe_h, knope_h, krope_h, vT_h, attn_h);
  // output projection (128x256 2-phase, f32 out): 256 blocks = full machine
  gemm_out<<<dim3(8, 32), 512, 0, stream>>>(attn_h, wo_h, out);
}

// Round 15
// 438.380 us; speedup vs baseline: 1.0422x; 1.0422x over previous
//
#include <hip/hip_runtime.h>
#include <stdint.h>

typedef _Float16 f16x8 __attribute__((ext_vector_type(8)));
typedef _Float16 f16x4 __attribute__((ext_vector_type(4)));
typedef float fx4 __attribute__((ext_vector_type(4)));

static constexpr int S_LEN = 2048;
static constexpr int BATCH = 2;
static constexpr int TOKENS = BATCH * S_LEN;   // 4096
static constexpr int DIM = 2048;
static constexpr int NH = 16;
static constexpr int QR = 1536;
static constexpr int KVR = 512;
static constexpr int DN = 128;
static constexpr int DR = 64;
static constexpr int DV = 128;

// async global->LDS, 16B per lane; LDS dest = wave-uniform base, HW adds lane*16
__device__ __forceinline__ void async16(const _Float16* g, _Float16* lds_base_uniform) {
  __builtin_amdgcn_global_load_lds(
      (const __attribute__((address_space(1))) void*)g,
      (__attribute__((address_space(3))) void*)lds_base_uniform, 16, 0, 0);
}

// raw barrier WITHOUT the implicit vmcnt(0) drain of __syncthreads
__device__ __forceinline__ void bar() {
  asm volatile("" ::: "memory");
  __builtin_amdgcn_s_barrier();
  asm volatile("" ::: "memory");
}
#define VMWAIT(n) asm volatile("s_waitcnt vmcnt(" #n ")" ::: "memory")

// intra-16-lane rotate via DPP (VALU, ~4cyc vs ~35cyc ds_swizzle)
#define ROR16(x, ctrl) \
  __uint_as_float(__builtin_amdgcn_update_dpp(__float_as_uint(x), __float_as_uint(x), \
                                              (ctrl), 0xF, 0xF, false))

// sin/cos via v_sin/v_cos (input = revolutions), manual range reduction
__device__ __forceinline__ void sincos_rev(float ang, float* sn, float* cs) {
  float rev = ang * 0.15915494309189535f;
  rev -= floorf(rev);
  *sn = __builtin_amdgcn_sinf(rev);   // sin(2*pi*rev)
  *cs = __builtin_amdgcn_cosf(rev);
}

// ---------------- fused f32 -> f16 conversion (+ optional per-col norm fold)
struct CvtSegs {
  const float* src[8];
  _Float16* dst[8];
  const float* nw[8];   // per-column weight to fold (or nullptr)
  int nmod[8];          // column count (multiple of 4)
  int n4[8];
  int cum[9];
};
__global__ __launch_bounds__(256) void cvt_all(CvtSegs s) {
  const int b = blockIdx.x;
  int seg = 0;
#pragma unroll
  for (int k = 0; k < 7; ++k) seg += (b >= s.cum[seg + 1]) ? 1 : 0;
  const int i = (b - s.cum[seg]) * 256 + threadIdx.x;
  if (i >= s.n4[seg]) return;
  fx4 v = *(const fx4*)(s.src[seg] + (size_t)i * 4);
  if (s.nw[seg]) {
    const int c0 = (int)(((size_t)i * 4) % (size_t)s.nmod[seg]);
    fx4 wv = *(const fx4*)(s.nw[seg] + c0);
    v[0] *= wv[0]; v[1] *= wv[1]; v[2] *= wv[2]; v[3] *= wv[3];
  }
  f16x4 o;
  o[0] = (_Float16)v[0]; o[1] = (_Float16)v[1];
  o[2] = (_Float16)v[2]; o[3] = (_Float16)v[3];
  *(f16x4*)(s.dst[seg] + (size_t)i * 4) = o;
}

// ---------------- per-row rsqrt factors for qc/kvc (one tiny pass) ---------
__global__ __launch_bounds__(256) void rownorm(const _Float16* __restrict__ qc,
                                               const _Float16* __restrict__ kvc,
                                               float* __restrict__ rq,
                                               float* __restrict__ rkv) {
  const int idx = blockIdx.x * 4 + (threadIdx.x >> 6);   // one wave per row
  const int lane = threadIdx.x & 63;
  const bool isq = idx < TOKENS;
  const int row = isq ? idx : idx - TOKENS;
  const int NC = isq ? QR : KVR;
  const f16x8* p = (const f16x8*)((isq ? qc : kvc) + (size_t)row * NC);
  float ss = 0.f;
  for (int c = lane; c < NC / 8; c += 64) {
    f16x8 v = p[c];
#pragma unroll
    for (int e = 0; e < 8; ++e) { const float x = (float)v[e]; ss += x * x; }
  }
#pragma unroll
  for (int d = 1; d < 64; d <<= 1) ss += __shfl_xor(ss, d);
  if (lane == 0) {
    const float rv = rsqrtf(ss / (float)NC + 1e-6f);
    if (isq) rq[row] = rv; else rkv[row] = rv;
  }
}

// ---------------- 128x128 NT GEMM (down-proj only), 3-buf counted vmcnt ----
// MODE 5: col<1536 -> qc; <2048 -> kvc; <2112 -> krope WITH RoPE in-epilogue.
template <int MODE>
__global__ __launch_bounds__(256) void gemm_nt(const _Float16* __restrict__ A,
                                               const _Float16* __restrict__ W,
                                               void* __restrict__ C0v,
                                               void* __restrict__ C1v,
                                               void* __restrict__ C2v,
                                               int M, int N, int K) {
  __shared__ __attribute__((aligned(16))) _Float16 As[3][128 * 32];
  __shared__ __attribute__((aligned(16))) _Float16 Ws[3][128 * 32];
  const int tid = threadIdx.x;
  const int lane = tid & 63;
  const int wave = tid >> 6;
  const int wr = (wave >> 1) * 64;
  const int wc = (wave & 1) * 64;
  const int m16 = lane & 15;
  const int quad = lane >> 4;
  const int swz = (m16 >> 1) & 3;
  const int m0 = blockIdx.y * 128;
  const int n0 = blockIdx.x * 128;

  auto stage = [&](int buf, int k0) {
#pragma unroll
    for (int p = 0; p < 2; ++p) {
      const int cb = p * 256 + wave * 64;
      const int ch = cb + lane;
      const int r = ch >> 2;
      const int c8 = ((ch & 3) ^ ((r >> 1) & 3)) * 8;
      async16(A + (size_t)(m0 + r) * K + k0 + c8, &As[buf][cb * 8]);
      async16(W + (size_t)(n0 + r) * K + k0 + c8, &Ws[buf][cb * 8]);
    }
  };

  const fx4 fz = {0.f, 0.f, 0.f, 0.f};
  fx4 acc[4][4];
#pragma unroll
  for (int i = 0; i < 4; ++i)
#pragma unroll
    for (int j = 0; j < 4; ++j) acc[i][j] = fz;

  const int nkt = K >> 5;
  stage(0, 0);
  stage(1, 32);
  int cur = 0;
  for (int kt = 0; kt < nkt; ++kt) {
    if (kt + 1 < nkt) { VMWAIT(4); } else { VMWAIT(0); }
    bar();
    if (kt + 2 < nkt) {
      int b2 = cur + 2; if (b2 >= 3) b2 -= 3;
      stage(b2, (kt + 2) * 32);
    }
    const _Float16* as = As[cur];
    const _Float16* ws = Ws[cur];
    f16x8 af[4], wf[4];
#pragma unroll
    for (int i = 0; i < 4; ++i)
      af[i] = *(const f16x8*)(&as[((wr + i * 16 + m16) * 4 + (quad ^ swz)) * 8]);
#pragma unroll
    for (int j = 0; j < 4; ++j)
      wf[j] = *(const f16x8*)(&ws[((wc + j * 16 + m16) * 4 + (quad ^ swz)) * 8]);
#pragma unroll
    for (int i = 0; i < 4; ++i)
#pragma unroll
      for (int j = 0; j < 4; ++j)
        acc[i][j] = __builtin_amdgcn_mfma_f32_16x16x32_f16(af[i], wf[j], acc[i][j], 0, 0, 0);
    if (++cur == 3) cur = 0;
  }

#pragma unroll
  for (int j = 0; j < 4; ++j) {
    const int col = n0 + wc + j * 16 + m16;
    if (MODE == 5) {
      if (col < 2048) {
#pragma unroll
        for (int i = 0; i < 4; ++i)
#pragma unroll
          for (int r = 0; r < 4; ++r) {
            const size_t row = (size_t)(m0 + wr + i * 16 + quad * 4 + r);
            const _Float16 v = (_Float16)acc[i][j][r];
            if (col < 1536) ((_Float16*)C0v)[row * 1536 + col] = v;
            else            ((_Float16*)C1v)[row * 512 + col - 1536] = v;
          }
      } else if (col < 2112) {
        const int d = col - 2048;
        const int pidx = d >> 1;
        const bool odd = (d & 1);
        const float fr = exp2f(-(float)pidx * 0.4152410118609203f);
#pragma unroll
        for (int i = 0; i < 4; ++i)
#pragma unroll
          for (int r = 0; r < 4; ++r) {
            const size_t row = (size_t)(m0 + wr + i * 16 + quad * 4 + r);
            const int spos = (int)(row & (S_LEN - 1));
            float sn, cs;
            sincos_rev((float)spos * fr, &sn, &cs);
            const float own = acc[i][j][r];
            const float oth = __shfl_xor(own, 1);
            const float res = odd ? (oth * sn + own * cs) : (own * cs - oth * sn);
            ((_Float16*)C2v)[row * 64 + d] = (_Float16)res;
          }
      }
    } else {
      if (col < N) {
#pragma unroll
        for (int i = 0; i < 4; ++i)
#pragma unroll
          for (int r = 0; r < 4; ++r) {
            const size_t row = (size_t)(m0 + wr + i * 16 + quad * 4 + r);
            ((float*)C0v)[row * N + col] = acc[i][j][r];
          }
      }
    }
  }
}

// ---------------- 256x256 8-wave 4-phase GEMM (up-proj, T2+T3+T4+T5) -------
// (verified R10) BK=64, dbuf 128KB LDS, half-tile prefetch, counted vmcnt.
template <int MODE>
__global__ __launch_bounds__(512, 2) void gemm256(
    const _Float16* __restrict__ Aq, const _Float16* __restrict__ Wq,
    const _Float16* __restrict__ Akv, const _Float16* __restrict__ Wkv,
    const float* __restrict__ rq, const float* __restrict__ rkv,
    void* __restrict__ C0, void* __restrict__ C1,
    void* __restrict__ C2, void* __restrict__ C3, int Kq) {
  __shared__ __attribute__((aligned(16))) _Float16 As[2][256 * 64];  // 64 KB
  __shared__ __attribute__((aligned(16))) _Float16 Ws[2][256 * 64];  // 64 KB

  const int tid = threadIdx.x;
  const int lane = tid & 63;
  const int wave = tid >> 6;           // 0..7
  const int wrow = wave >> 2;          // 0..1
  const int wcol = wave & 3;           // 0..3
  const int m16 = lane & 15;
  const int quad = lane >> 4;
  const int m0 = blockIdx.y * 256;

  const bool isq = (MODE == 0) || ((int)blockIdx.x < 12);
  const int n0 = (MODE == 0) ? blockIdx.x * 256
                             : (isq ? blockIdx.x * 256 : (blockIdx.x - 12) * 256);
  const _Float16* A = (MODE == 0) ? Aq : (isq ? Aq : Akv);
  const _Float16* W = (MODE == 0) ? Wq : (isq ? Wq : Wkv);
  const int K = (MODE == 0) ? Kq : (isq ? QR : KVR);

  auto stageHalf = [&](int buf, int k0, int tensor, int h) {
#pragma unroll
    for (int k = 0; k < 2; ++k) {
      const int cb = (wave * 2 + k) * 64;      // chunk base in half (0..1023)
      const int ch = cb + lane;
      const int r = ch >> 3;                   // local row 0..127
      const int gc = (ch & 7) ^ (r & 7);       // pre-swizzled source chunk
      const int grow = h * 128 + r;
      if (tensor == 0)
        async16(A + (size_t)(m0 + grow) * K + k0 + gc * 8,
                &As[buf][(h * 1024 + cb) * 8]);
      else
        async16(W + (size_t)(n0 + grow) * K + k0 + gc * 8,
                &Ws[buf][(h * 1024 + cb) * 8]);
    }
  };

  const fx4 fz = {0.f, 0.f, 0.f, 0.f};
  fx4 acc[8][4];
#pragma unroll
  for (int i = 0; i < 8; ++i)
#pragma unroll
    for (int j = 0; j < 4; ++j) acc[i][j] = fz;

  f16x8 af[4][2], wf0[2][2], wf1[2][2];

  auto rdA = [&](const _Float16* as, int mh) {
#pragma unroll
    for (int mg = 0; mg < 4; ++mg)
#pragma unroll
      for (int ks = 0; ks < 2; ++ks) {
        const int row = mh * 128 + mg * 32 + wrow * 16 + m16;
        af[mg][ks] = *(const f16x8*)(&as[(row * 8 + ((ks * 4 + quad) ^ (m16 & 7))) * 8]);
      }
  };
  auto rdB = [&](const _Float16* ws, int nh, f16x8 wf[2][2]) {
#pragma unroll
    for (int ng = 0; ng < 2; ++ng)
#pragma unroll
      for (int ks = 0; ks < 2; ++ks) {
        const int row = nh * 128 + ng * 64 + wcol * 16 + m16;
        wf[ng][ks] = *(const f16x8*)(&ws[(row * 8 + ((ks * 4 + quad) ^ (m16 & 7))) * 8]);
      }
  };
  auto quadMFMA = [&](int mh, int nh, f16x8 wf[2][2]) {
    __builtin_amdgcn_s_setprio(1);
#pragma unroll
    for (int ks = 0; ks < 2; ++ks)
#pragma unroll
      for (int mg = 0; mg < 4; ++mg)
#pragma unroll
        for (int ng = 0; ng < 2; ++ng)
          acc[mh * 4 + mg][nh * 2 + ng] = __builtin_amdgcn_mfma_f32_16x16x32_f16(
              af[mg][ks], wf[ng][ks], acc[mh * 4 + mg][nh * 2 + ng], 0, 0, 0);
    __builtin_amdgcn_s_setprio(0);
  };

  const int nkt = K >> 6;
  stageHalf(0, 0, 0, 0);
  stageHalf(0, 0, 1, 0);
  stageHalf(0, 0, 1, 1);
  stageHalf(0, 0, 0, 1);

  for (int t = 0; t < nkt; ++t) {
    const int cur = t & 1;
    const int nb = cur ^ 1;
    const int k0n = (t + 1) * 64;
    const bool more = (t + 1 < nkt);
    const _Float16* as = As[cur];
    const _Float16* ws = Ws[cur];

    VMWAIT(4);
    bar();
    rdA(as, 0);
    rdB(ws, 0, wf0);
    if (more) stageHalf(nb, k0n, 0, 0);      // Ah0(t+1)
    quadMFMA(0, 0, wf0);

    if (more) { VMWAIT(4); } else { VMWAIT(2); }
    bar();
    rdB(ws, 1, wf1);
    if (more) stageHalf(nb, k0n, 1, 0);      // Bh0(t+1)
    quadMFMA(0, 1, wf1);

    if (more) { VMWAIT(4); } else { VMWAIT(0); }
    bar();
    rdA(as, 1);
    if (more) stageHalf(nb, k0n, 1, 1);      // Bh1(t+1)
    quadMFMA(1, 1, wf1);

    bar();
    if (more) stageHalf(nb, k0n, 0, 1);      // Ah1(t+1)
    quadMFMA(1, 0, wf0);
  }

  // ---- epilogue ----
  float rsq[8][4];
  if (MODE == 1) {
    const float* rs = isq ? rq : rkv;
#pragma unroll
    for (int mg = 0; mg < 8; ++mg)
#pragma unroll
      for (int r = 0; r < 4; ++r)
        rsq[mg][r] = rs[m0 + mg * 32 + wrow * 16 + quad * 4 + r];
  }

#pragma unroll
  for (int ng = 0; ng < 4; ++ng) {
    const int col = n0 + ng * 64 + wcol * 16 + m16;
    if (MODE == 0) {
#pragma unroll
      for (int mg = 0; mg < 8; ++mg)
#pragma unroll
        for (int r = 0; r < 4; ++r) {
          const size_t row = (size_t)(m0 + mg * 32 + wrow * 16 + quad * 4 + r);
          ((float*)C0)[row * 2048 + col] = acc[mg][ng][r];
        }
    } else if (isq) {
#pragma unroll
      for (int mg = 0; mg < 8; ++mg)
#pragma unroll
        for (int r = 0; r < 4; ++r) {
          const size_t row = (size_t)(m0 + mg * 32 + wrow * 16 + quad * 4 + r);
          const _Float16 v = (_Float16)(acc[mg][ng][r] * rsq[mg][r]);
          if (col < 2048) ((_Float16*)C0)[row * 2048 + col] = v;
          else ((_Float16*)C1)[row * 1024 + col - 2048] = v;
        }
    } else {
      const int head = col >> 8;
      const int sub = col & 255;
      if (sub < 128) {
#pragma unroll
        for (int mg = 0; mg < 8; ++mg)
#pragma unroll
          for (int r = 0; r < 4; ++r) {
            const size_t row = (size_t)(m0 + mg * 32 + wrow * 16 + quad * 4 + r);
            ((_Float16*)C2)[row * 2048 + head * 128 + sub] =
                (_Float16)(acc[mg][ng][r] * rsq[mg][r]);
          }
      } else {
        const int dv = sub - 128;
#pragma unroll
        for (int mg = 0; mg < 8; ++mg) {
          f16x4 v;
#pragma unroll
          for (int r = 0; r < 4; ++r) v[r] = (_Float16)(acc[mg][ng][r] * rsq[mg][r]);
          *(f16x4*)(&((_Float16*)C3)[(size_t)(head * 128 + dv) * TOKENS + m0 +
                                     mg * 32 + wrow * 16 + quad * 4]) = v;
        }
      }
    }
  }
}

// ---------------- 128x256 8-wave 2-phase GEMM (out-proj) -------------------
// 256 blocks = exactly 1/CU; this grid-fill is why this structure works here.
__global__ __launch_bounds__(512, 1) void gemm_out(
    const _Float16* __restrict__ A,    // attn [4096, 2048]
    const _Float16* __restrict__ W,    // wo   [2048, 2048]
    float* __restrict__ C) {           // out  [4096, 2048] f32
  __shared__ __attribute__((aligned(16))) _Float16 As[2][128 * 64];  // 32 KB
  __shared__ __attribute__((aligned(16))) _Float16 Ws[2][256 * 64];  // 64 KB

  const int tid = threadIdx.x;
  const int lane = tid & 63;
  const int wave = tid >> 6;           // 0..7
  const int wrow = wave >> 2;          // 0..1
  const int wcol = wave & 3;           // 0..3
  const int m16 = lane & 15;
  const int quad = lane >> 4;
  const int m0 = blockIdx.y * 128;
  const int n0 = blockIdx.x * 256;
  const int K = NH * DV;               // 2048

  auto stageA = [&](int buf, int k0) {
#pragma unroll
    for (int k = 0; k < 2; ++k) {
      const int cb = (wave * 2 + k) * 64;    // 0..960 (1024 chunks = 128x8)
      const int ch = cb + lane;
      const int r = ch >> 3;                 // 0..127
      const int gc = (ch & 7) ^ (r & 7);
      async16(A + (size_t)(m0 + r) * K + k0 + gc * 8, &As[buf][cb * 8]);
    }
  };
  auto stageW = [&](int buf, int k0, int h) {
#pragma unroll
    for (int k = 0; k < 2; ++k) {
      const int cb = (wave * 2 + k) * 64;
      const int ch = cb + lane;
      const int r = ch >> 3;
      const int gc = (ch & 7) ^ (r & 7);
      async16(W + (size_t)(n0 + h * 128 + r) * K + k0 + gc * 8,
              &Ws[buf][(h * 1024 + cb) * 8]);
    }
  };

  const fx4 fz = {0.f, 0.f, 0.f, 0.f};
  fx4 acc[4][4];
#pragma unroll
  for (int i = 0; i < 4; ++i)
#pragma unroll
    for (int j = 0; j < 4; ++j) acc[i][j] = fz;

  f16x8 af[4][2], wf0[2][2], wf1[2][2];

  auto rdA = [&](const _Float16* as) {
#pragma unroll
    for (int mg = 0; mg < 4; ++mg)
#pragma unroll
      for (int ks = 0; ks < 2; ++ks) {
        const int row = mg * 32 + wrow * 16 + m16;
        af[mg][ks] = *(const f16x8*)(&as[(row * 8 + ((ks * 4 + quad) ^ (m16 & 7))) * 8]);
      }
  };
  auto rdB = [&](const _Float16* ws, int nh, f16x8 wf[2][2]) {
#pragma unroll
    for (int ng = 0; ng < 2; ++ng)
#pragma unroll
      for (int ks = 0; ks < 2; ++ks) {
        const int row = nh * 128 + ng * 64 + wcol * 16 + m16;
        wf[ng][ks] = *(const f16x8*)(&ws[(row * 8 + ((ks * 4 + quad) ^ (m16 & 7))) * 8]);
      }
  };
  auto halfMFMA = [&](int nh, f16x8 wf[2][2]) {
    __builtin_amdgcn_s_setprio(1);
#pragma unroll
    for (int ks = 0; ks < 2; ++ks)
#pragma unroll
      for (int mg = 0; mg < 4; ++mg)
#pragma unroll
        for (int ng = 0; ng < 2; ++ng)
          acc[mg][nh * 2 + ng] = __builtin_amdgcn_mfma_f32_16x16x32_f16(
              af[mg][ks], wf[ng][ks], acc[mg][nh * 2 + ng], 0, 0, 0);
    __builtin_amdgcn_s_setprio(0);
  };

  const int nkt = K >> 6;              // 32
  stageA(0, 0);
  stageW(0, 0, 0);
  stageW(0, 0, 1);

  for (int t = 0; t < nkt; ++t) {
    const int cur = t & 1;
    const int nb = cur ^ 1;
    const int k0n = (t + 1) * 64;
    const bool more = (t + 1 < nkt);
    const _Float16* as = As[cur];
    const _Float16* ws = Ws[cur];

    // phase 0: A(t), Bh0(t) are the oldest 4 of the 6 outstanding
    VMWAIT(2);
    bar();
    rdA(as);
    rdB(ws, 0, wf0);
    if (more) stageA(nb, k0n);
    halfMFMA(0, wf0);

    // phase 1: Bh1(t) landed when <=2 remain (A(t+1) is the newest 2)
    if (more) { VMWAIT(2); } else { VMWAIT(0); }
    bar();
    rdB(ws, 1, wf1);
    if (more) { stageW(nb, k0n, 0); stageW(nb, k0n, 1); }
    halfMFMA(1, wf1);
  }

  // ---- epilogue: f32 C ----
#pragma unroll
  for (int ng = 0; ng < 4; ++ng) {
    const int col = n0 + ng * 64 + wcol * 16 + m16;
#pragma unroll
    for (int mg = 0; mg < 4; ++mg)
#pragma unroll
      for (int r = 0; r < 4; ++r) {
        const size_t row = (size_t)(m0 + mg * 32 + wrow * 16 + quad * 4 + r);
        C[row * 2048 + col] = acc[mg][ng][r];
      }
  }
}

// ---------------- causal flash attention (verified R10/R11: ~112us) --------
__global__ __launch_bounds__(512, 2) void mla_attn(
    const _Float16* __restrict__ qn,   // [T, NH*128]
    const _Float16* __restrict__ qp,   // [T, NH*64]  RAW (rope applied here)
    const _Float16* __restrict__ kn,   // [T, NH*128]
    const _Float16* __restrict__ kr,   // [T, 64]     roped
    const _Float16* __restrict__ vT,   // [NH*128, T]
    _Float16* __restrict__ out)        // [T, NH*128]
{
  __shared__ __attribute__((aligned(16))) _Float16 Ks[2][768 * 8];  // 24 KB
  __shared__ __attribute__((aligned(16))) _Float16 Vs[2][512 * 8];  // 16 KB
  __shared__ __attribute__((aligned(16))) _Float16 Ps[8][16][40];   // 10 KB

  const int bid = blockIdx.x;          // 512 = 16 q-tiles (longest first) x 32 (b,h)
  const int j = bid >> 5;
  const int bh = bid & 31;
  const int b = bh >> 4;
  const int h = bh & 15;
  const int q16 = 15 - j;              // longest-first
  const int qb = q16 * 128;
  const int tok0 = b * S_LEN;

  const int tid = threadIdx.x;
  const int lane = tid & 63;
  const int wave = tid >> 6;           // 0..7
  const int m16 = lane & 15;
  const int quad = lane >> 4;
  const int R0 = qb + wave * 16;

  auto stageKV = [&](int buf, int kbase) {
#pragma unroll
    for (int jj = 0; jj < 3; ++jj) {
      const int idx = wave * 3 + jj;          // 0..23; 20 used
      if (idx < 12) {
        const int ch = idx * 2 + (lane >> 5);
        const int key = lane & 31;
        const _Float16* g = (ch < 16)
            ? kn + (size_t)(tok0 + kbase + key) * 2048 + h * 128 + ch * 8
            : kr + (size_t)(tok0 + kbase + key) * 64 + (ch - 16) * 8;
        async16(g, &Ks[buf][idx * 512]);
      } else if (idx < 20) {
        const int iv = idx - 12;              // 0..7
        const int p = iv * 64 + lane;
        const int L = p ^ ((p >> 3) & 3);     // involutive source pre-swizzle
        const int dv = L >> 2;
        const int qcc = L & 3;
        async16(vT + (size_t)(h * 128 + dv) * TOKENS + tok0 + kbase + qcc * 8,
                &Vs[buf][iv * 512]);
      }
    }
  };

  const float scale2 = 0.07216878364870323f * 1.4426950408889634f;  // /sqrt(192), log2 dom
  const fx4 fz = {0.f, 0.f, 0.f, 0.f};

  // ---- Q fragments (A-layout); RoPE applied to the qp fragments in-reg ----
  f16x8 qf[6];
  {
    const int srow = qb + wave * 16 + m16;     // seq position (0..2047)
    const size_t t = (size_t)(tok0 + srow);
#pragma unroll
    for (int kk = 0; kk < 4; ++kk)
      qf[kk] = *(const f16x8*)(qn + t * 2048 + h * 128 + kk * 32 + quad * 8);
#pragma unroll
    for (int kk = 0; kk < 2; ++kk) {
      f16x8 v = *(const f16x8*)(qp + t * 1024 + h * 64 + kk * 32 + quad * 8);
      f16x8 o;
      const int i0 = kk * 16 + quad * 4;       // rope pair index base
#pragma unroll
      for (int jj = 0; jj < 4; ++jj) {
        const float ang = (float)srow * exp2f(-(float)(i0 + jj) * 0.4152410118609203f);
        float sn, cs;
        sincos_rev(ang, &sn, &cs);
        const float x1 = (float)v[2 * jj], x2 = (float)v[2 * jj + 1];
        o[2 * jj]     = (_Float16)(x1 * cs - x2 * sn);
        o[2 * jj + 1] = (_Float16)(x1 * sn + x2 * cs);
      }
      qf[4 + kk] = o;
    }
  }

  fx4 oacc[9];                         // [8] accumulates row-sums (P x ones)
#pragma unroll
  for (int n = 0; n < 9; ++n) oacc[n] = fz;
  float mst[4];
#pragma unroll
  for (int r = 0; r < 4; ++r) mst[r] = -3.0e38f;
  f16x8 vones;
#pragma unroll
  for (int e = 0; e < 8; ++e) vones[e] = (_Float16)1.0f;

  const int nkt = (qb >> 5) + 4;       // key tiles: 0 .. qb+127 (4..64)

  stageKV(0, 0);
  for (int kt = 0; kt < nkt; ++kt) {
    const int kbase = kt * 32;
    __syncthreads();
    if (kt + 1 < nkt) stageKV((kt + 1) & 1, kbase + 32);

    const bool live = (kbase <= R0 + 15);
    if (!live) continue;
    const _Float16* ks = Ks[kt & 1];
    const _Float16* vs = Vs[kt & 1];

    // ---- S = Q K^T ----
    fx4 sc[2];
    sc[0] = fz; sc[1] = fz;
    __builtin_amdgcn_s_setprio(1);
#pragma unroll
    for (int kk = 0; kk < 6; ++kk) {
#pragma unroll
      for (int n = 0; n < 2; ++n) {
        f16x8 kf = *(const f16x8*)(&ks[(kk * 128 + quad * 32 + n * 16 + m16) * 8]);
        sc[n] = __builtin_amdgcn_mfma_f32_16x16x32_f16(qf[kk], kf, sc[n], 0, 0, 0);
      }
    }
    __builtin_amdgcn_s_setprio(0);

    // V fragments from LDS (swizzled read)
    f16x8 vf[8];
#pragma unroll
    for (int n8 = 0; n8 < 8; ++n8) {
      const int c0 = (n8 * 16 + m16) * 4 + quad;
      vf[n8] = *(const f16x8*)(&vs[(c0 ^ ((c0 >> 3) & 3)) * 8]);
    }

    // ---- online softmax: max-reduce only on growth; no sum-reduce at all ----
    const bool needmask = (kbase + 31 > R0);
    float alpha[4];
    bool any_upd = false;
#pragma unroll
    for (int r = 0; r < 4; ++r) {
      float v0 = sc[0][r] * scale2;
      float v1 = sc[1][r] * scale2;
      if (needmask) {
        const int qrow = R0 + quad * 4 + r;
        if (kbase + m16 > qrow)      v0 = -3.0e38f;
        if (kbase + 16 + m16 > qrow) v1 = -3.0e38f;
      }
      const float pre = fmaxf(v0, v1);
      float al = 1.0f;
      if (__any(pre > mst[r] + 10.0f)) {       // rare after warm-up
        float mx = pre;
        mx = fmaxf(mx, ROR16(mx, 0x128));
        mx = fmaxf(mx, ROR16(mx, 0x124));
        mx = fmaxf(mx, ROR16(mx, 0x122));
        mx = fmaxf(mx, ROR16(mx, 0x121));
        const float mn = fmaxf(mst[r], mx);
        al = exp2f(mst[r] - mn);
        mst[r] = mn;
        any_upd = true;
      }
      alpha[r] = al;
      const float p0 = exp2f(v0 - mst[r]);
      const float p1 = exp2f(v1 - mst[r]);
      _Float16* pr = &Ps[wave][quad * 4 + r][0];
      pr[m16] = (_Float16)p0;
      pr[16 + m16] = (_Float16)p1;
    }
    if (any_upd) {
#pragma unroll
      for (int n8 = 0; n8 < 9; ++n8)
#pragma unroll
        for (int r = 0; r < 4; ++r) oacc[n8][r] *= alpha[r];
    }

    // ---- O += P V ; row-sums accumulate via ones-column MFMA ----
    f16x8 pf = *(const f16x8*)(&Ps[wave][m16][quad * 8]);
    __builtin_amdgcn_s_setprio(1);
#pragma unroll
    for (int n8 = 0; n8 < 8; ++n8)
      oacc[n8] = __builtin_amdgcn_mfma_f32_16x16x32_f16(pf, vf[n8], oacc[n8], 0, 0, 0);
    oacc[8] = __builtin_amdgcn_mfma_f32_16x16x32_f16(pf, vones, oacc[8], 0, 0, 0);
    __builtin_amdgcn_s_setprio(0);
  }

  // ---- epilogue: normalize by oacc[8] (row sums; all cols equal) ----
  float inv[4];
#pragma unroll
  for (int r = 0; r < 4; ++r) inv[r] = 1.0f / oacc[8][r];
#pragma unroll
  for (int n8 = 0; n8 < 8; ++n8) {
#pragma unroll
    for (int r = 0; r < 4; ++r) {
      const size_t t = (size_t)(tok0 + qb + wave * 16 + quad * 4 + r);
      out[t * 2048 + h * 128 + n8 * 16 + m16] = (_Float16)(oacc[n8][r] * inv[r]);
    }
  }
}

// ---------------- launch ----------------------------------------------------
extern "C" void kernel_launch(void* const* d_in, const int* in_sizes, int n_in,
                              void* d_out, int out_size, void* d_ws, size_t ws_size,
                              hipStream_t stream) {
  const float* x         = (const float*)d_in[0];
  const float* wq_down   = (const float*)d_in[1];
  const float* q_norm_w  = (const float*)d_in[2];
  const float* wq_up     = (const float*)d_in[3];
  const float* wq_rope   = (const float*)d_in[4];
  const float* wkv_down  = (const float*)d_in[5];
  const float* kv_norm_w = (const float*)d_in[6];
  const float* wkv_up    = (const float*)d_in[7];
  const float* wk_rope   = (const float*)d_in[8];
  const float* wo        = (const float*)d_in[9];
  float* out = (float*)d_out;

  char* ws = (char*)d_ws;
  size_t off = 0;
  auto alloc = [&](size_t bytes) {
    char* p = ws + off;
    off += (bytes + 255) & ~(size_t)255;
    return p;
  };
  _Float16* x_h     = (_Float16*)alloc((size_t)TOKENS * DIM * 2);
  _Float16* wA_h    = (_Float16*)alloc((size_t)2176 * DIM * 2);      // wq_down|wkv_down|wk_rope (+pad)
  _Float16* wquqr_h = (_Float16*)alloc((size_t)3072 * QR * 2);       // (wq_up|wq_rope) . q_norm
  _Float16* wkvu_h  = (_Float16*)alloc((size_t)NH * 256 * KVR * 2);  // wkv_up . kv_norm
  _Float16* wo_h    = (_Float16*)alloc((size_t)DIM * NH * DV * 2);
  _Float16* qc_h    = (_Float16*)alloc((size_t)TOKENS * QR * 2);     // RAW (un-normalized)
  _Float16* kvc_h   = (_Float16*)alloc((size_t)TOKENS * KVR * 2);    // RAW
  _Float16* qnope_h = (_Float16*)alloc((size_t)TOKENS * 2048 * 2);
  _Float16* qpe_h   = (_Float16*)alloc((size_t)TOKENS * 1024 * 2);
  _Float16* knope_h = (_Float16*)alloc((size_t)TOKENS * 2048 * 2);
  _Float16* vT_h    = (_Float16*)alloc((size_t)2048 * TOKENS * 2);
  _Float16* krope_h = (_Float16*)alloc((size_t)TOKENS * DR * 2);     // roped in down-proj
  _Float16* attn_h  = (_Float16*)alloc((size_t)TOKENS * 2048 * 2);
  float* rq_h       = (float*)alloc((size_t)TOKENS * 4);
  float* rkv_h      = (float*)alloc((size_t)TOKENS * 4);

  // ---- one fused conversion dispatch (norm weights folded into up-proj W) --
  CvtSegs cs;
  const float* srcs[8] = {x, wq_down, wq_up, wq_rope, wkv_down, wk_rope, wkv_up, wo};
  _Float16* dsts[8] = {x_h, wA_h, wquqr_h, wquqr_h + (size_t)2048 * QR,
                       wA_h + (size_t)1536 * DIM, wA_h + (size_t)2048 * DIM,
                       wkvu_h, wo_h};
  const float* nws[8] = {nullptr, nullptr, q_norm_w, q_norm_w, nullptr, nullptr,
                         kv_norm_w, nullptr};
  const int nmods[8] = {4, 4, QR, QR, 4, 4, KVR, 4};
  const size_t ns[8] = {(size_t)TOKENS * DIM, (size_t)QR * DIM, (size_t)2048 * QR,
                        (size_t)1024 * QR, (size_t)KVR * DIM, (size_t)DR * DIM,
                        (size_t)NH * 256 * KVR, (size_t)DIM * NH * DV};
  int cum = 0;
  for (int i = 0; i < 8; ++i) {
    cs.src[i] = srcs[i];
    cs.dst[i] = dsts[i];
    cs.nw[i] = nws[i];
    cs.nmod[i] = nmods[i];
    cs.n4[i] = (int)(ns[i] / 4);
    cs.cum[i] = cum;
    cum += (cs.n4[i] + 255) / 256;
  }
  cs.cum[8] = cum;
  cvt_all<<<dim3(cum), 256, 0, stream>>>(cs);

  const unsigned gm = TOKENS / 128;

  // fused down-projection (128^2): x -> qc | kvc | krope(+RoPE)
  gemm_nt<5><<<dim3(17, gm), 256, 0, stream>>>(x_h, wA_h, qc_h, kvc_h, krope_h,
                                               TOKENS, 2112, DIM);
  // per-row rsqrt factors (one wave per row)
  rownorm<<<dim3(2 * TOKENS / 4), 256, 0, stream>>>(qc_h, kvc_h, rq_h, rkv_h);
  // fused up-projections (256^2 4-phase): qc -> qnope|qpe ; kvc -> knope+vT
  gemm256<1><<<dim3(12 + 16, TOKENS / 256), 512, 0, stream>>>(
      qc_h, wquqr_h, kvc_h, wkvu_h, rq_h, rkv_h,
      qnope_h, qpe_h, knope_h, vT_h, 0);
  // attention: 512 blocks x 8 waves (128 q-rows each), longest-first
  mla_attn<<<dim3(512), 512, 0, stream>>>(qnope_h, qpe_h, knope_h, krope_h, vT_h, attn_h);
  // output projection (128x256 2-phase, f32 out): 256 blocks = full machine
  gemm_out<<<dim3(8, 32), 512, 0, stream>>>(attn_h, wo_h, out);
}